// Round 4
// baseline (173.984 us; speedup 1.0000x reference)
//
#include <hip/hip_runtime.h>
#include <cstddef>

#define BB 4
#define CC 512
#define NN 4096

using half8  = __attribute__((ext_vector_type(8))) _Float16;
using fp16x2 = __attribute__((ext_vector_type(2))) __fp16;
using short8 = __attribute__((ext_vector_type(8))) short;
using us8    = __attribute__((ext_vector_type(8))) unsigned short;
using f32x4  = __attribute__((ext_vector_type(4))) float;
using f32x16 = __attribute__((ext_vector_type(16))) float;

__device__ __forceinline__ unsigned short f2bf(float x) {
    unsigned int u = __float_as_uint(x);
    u += 0x7fffu + ((u >> 16) & 1u);
    return (unsigned short)(u >> 16);
}

// ---------------- Kernel 0: weight conversion to fp16 ----------------
// Wc16 [192][512] = cat(Wf, Wg*log2e, Wh); Wv16 [512][64]
__global__ __launch_bounds__(256) void prep_kernel(
    const float* __restrict__ Wf, const float* __restrict__ Wg,
    const float* __restrict__ Wh, const float* __restrict__ Wv,
    _Float16* __restrict__ Wc16, _Float16* __restrict__ Wv16)
{
    int idx = blockIdx.x * 256 + threadIdx.x;
    int stride = gridDim.x * 256;
    const int N1 = 192 * 512, N2 = 512 * 64;
    for (int i = idx; i < N1 + N2; i += stride) {
        if (i < N1) {
            int row = i >> 9, c = i & 511;
            const float* src = (row < 64) ? Wf : ((row < 128) ? Wg : Wh);
            float sc = (row >= 64 && row < 128) ? 1.4426950408889634f : 1.0f;
            Wc16[i] = (_Float16)(sc * src[(row & 63) * 512 + c]);
        } else {
            int k = i - N1;
            Wv16[k] = (_Float16)Wv[k];
        }
    }
}

// ---------------- Kernel 1: projections f,g,h — 16-i tiles, 4 blocks/CU ----------------
// grid 1024 (XCD-chunked): (b, i-chunk of 16). x tile [16 i][64 c] fp32
// double-buffered in LDS; register prefetch of x AND weights one chunk ahead.
// Half the per-wave LDS-read/cvt work of the 32-i version, 2x the TLP.
__global__ __launch_bounds__(256, 4) void proj_kernel(
    const float* __restrict__ x, const _Float16* __restrict__ Wc16,
    _Float16* __restrict__ Kf, _Float16* __restrict__ Qf,
    unsigned short* __restrict__ Vt)
{
    __shared__ float xsT[2][16][68];   // [buf][i][c], pad 68: 2-way banks, 16B rows
    const int t    = threadIdx.x;
    const int w    = t >> 6;
    const int lane = t & 63;
    const int lh   = lane & 15;
    const int qd   = lane >> 4;

    // XCD-chunked swizzle: consecutive v (same XCD) are consecutive i0 so the two
    // blocks sharing each 128B x-line hit the same L2.
    const int g  = blockIdx.x;
    const int v  = (g & 7) * 128 + (g >> 3);   // 1024 blocks, bijective
    const int b  = v >> 8;
    const int i0 = (v & 255) << 4;

    f32x4 acc[3];
    #pragma unroll
    for (int ot = 0; ot < 3; ot++) { acc[ot][0]=0.f; acc[ot][1]=0.f; acc[ot][2]=0.f; acc[ot][3]=0.f; }

    const int i4 = t & 3;            // i-group of 4
    const int cr = t >> 2;           // c-row 0..63
    const float* xbase = x + (size_t)b*CC*NN + i0 + i4*4;
    const _Float16* wbase = Wc16 + (size_t)(w*48 + lh)*512 + qd*8;

    float4 st0;
    half8  wcur[2][3], wnxt[2][3];

#define LOADX(ck) do {                                                        \
    st0 = *(const float4*)(xbase + (size_t)((ck)*64 + cr)*NN);                \
} while (0)
#define STOREX(p_) do {                                                       \
    xsT[p_][i4*4+0][cr] = st0.x; xsT[p_][i4*4+1][cr] = st0.y;                 \
    xsT[p_][i4*4+2][cr] = st0.z; xsT[p_][i4*4+3][cr] = st0.w;                 \
} while (0)
#define LOADW(ck, WD) do {                                                    \
    _Pragma("unroll")                                                         \
    for (int ks_ = 0; ks_ < 2; ks_++)                                         \
        _Pragma("unroll")                                                     \
        for (int ot_ = 0; ot_ < 3; ot_++)                                     \
            WD[ks_][ot_] = *(const half8*)(wbase + (size_t)(ot_*16)*512 + (ck)*64 + ks_*32); \
} while (0)

    LOADX(0); STOREX(0);
    LOADW(0, wcur);
    __syncthreads();

    #pragma unroll
    for (int ck = 0; ck < 8; ck++) {
        const int p = ck & 1;
        if (ck < 7) { LOADX(ck + 1); LOADW(ck + 1, wnxt); }

        #pragma unroll
        for (int ks = 0; ks < 2; ks++) {
            const float* xr = &xsT[p][lh][ks*32 + qd*8];
            f32x4 xa = *(const f32x4*)xr;
            f32x4 xb = *(const f32x4*)(xr + 4);
            union { fp16x2 h2[4]; half8 h8; } u;
            u.h2[0] = __builtin_amdgcn_cvt_pkrtz(xa[0], xa[1]);
            u.h2[1] = __builtin_amdgcn_cvt_pkrtz(xa[2], xa[3]);
            u.h2[2] = __builtin_amdgcn_cvt_pkrtz(xb[0], xb[1]);
            u.h2[3] = __builtin_amdgcn_cvt_pkrtz(xb[2], xb[3]);
            half8 xf = u.h8;
            #pragma unroll
            for (int ot = 0; ot < 3; ot++)
                acc[ot] = __builtin_amdgcn_mfma_f32_16x16x32_f16(wcur[ks][ot], xf, acc[ot], 0, 0, 0);
        }

        if (ck < 7) {
            STOREX(p ^ 1);
            #pragma unroll
            for (int ks_ = 0; ks_ < 2; ks_++)
                #pragma unroll
                for (int ot_ = 0; ot_ < 3; ot_++)
                    wcur[ks_][ot_] = wnxt[ks_][ot_];
        }
        __syncthreads();
    }
#undef LOADX
#undef STOREX
#undef LOADW

    #pragma unroll
    for (int ot = 0; ot < 3; ot++) {
        int g16 = w*3 + ot;          // 0..11
        int m   = g16 >> 2;
        int obase = (g16 & 3)*16 + qd*4;
        int ig = i0 + lh;
        #pragma unroll
        for (int r = 0; r < 4; r++) {
            float vv = acc[ot][r];
            int ol = obase + r;
            if (m == 0)       Kf[((size_t)b*NN + ig)*64 + ol] = (_Float16)vv;
            else if (m == 1)  Qf[((size_t)b*NN + ig)*64 + ol] = (_Float16)vv;
            else              Vt[((size_t)b*64 + ol)*NN + ig] = f2bf(vv);
        }
    }
}

// ---------------- Kernel 2: split-K flash attention, 32x32 swapped-QK^T ----------------
// grid 128*SPLITS: (b, j-tile of 128, split s). 4 waves, wave owns 32 j columns.
// S^T = mfma_32x32x16_f16(Kfrag, Qfrag)  -> j lane-local, i in regs.
// P -> PV A-fragment fully in-register: v_cvt_pk_bf16_f32 + v_permlane32_swap_b32 (T12).
// K/V staged via global_load_lds (16B, source-swizzled, linear LDS dest),
// 64-key chunks, double-buffered (32 KB LDS). [R1 measured-best version]
template<int SPLITS>
__global__ __launch_bounds__(256, 3) void attn_kernel(
    const _Float16* __restrict__ Kf, const _Float16* __restrict__ Qf,
    const unsigned short* __restrict__ Vt,
    _Float16* __restrict__ Po16, float* __restrict__ Pl)
{
    static_assert(NN % SPLITS == 0, "split");
    constexpr int KS  = NN / SPLITS;   // keys per split
    constexpr int NCH = KS / 64;       // 64-key chunks

    __shared__ __align__(16) unsigned short Kb2[2][64*64];  // [i][c] swizzled 16B blocks
    __shared__ __align__(16) unsigned short Vb2[2][64*64];  // [d][i] swizzled 16B blocks

    const int t    = threadIdx.x;
    const int wv   = t >> 6;
    const int lane = t & 63;
    const int il   = lane & 31;
    const int h    = lane >> 5;

    // bijective XCD swizzle: blocks sharing (b,s) (same K/V) land on one XCD
    const int p  = blockIdx.x;
    const int v  = (p & 7) * (SPLITS * 16) + (p >> 3);
    const int jt = v & 31;
    const int bs = v >> 5;
    const int b  = bs / SPLITS;
    const int s  = bs % SPLITS;
    const int j0w  = jt*128 + wv*32;
    const int koff = s * KS;

    // Q fragments (B-operand), hoisted: lane supplies Q[c = sl*16 + h*8 + e][j = j0w + il]
    half8 qfr[4];
    {
        const _Float16* qp = Qf + ((size_t)b*NN + j0w + il)*64 + h*8;
        #pragma unroll
        for (int sl = 0; sl < 4; sl++) qfr[sl] = *(const half8*)(qp + sl*16);
    }

    f32x16 o_acc[2];
    #pragma unroll
    for (int dt = 0; dt < 2; dt++)
        #pragma unroll
        for (int r = 0; r < 16; r++) o_acc[dt][r] = 0.f;
    float l4[4] = {0.f, 0.f, 0.f, 0.f};

    // Staging bases, hoisted. Two 16B slots per thread per buffer (K and V each):
    // linear LDS dest (wave-uniform base + lane*16), inverse-swizzled global SOURCE
    // (involution: slot c8 holds col block c8^(row&7)).
    const int slot0 = t, slot1 = 256 + t;
    const int ik0 = slot0 >> 3, sw0 = ((slot0 & 7) ^ (ik0 & 7)) << 3;
    const int ik1 = slot1 >> 3, sw1 = ((slot1 & 7) ^ (ik1 & 7)) << 3;
    const _Float16*       gk0 = Kf + ((size_t)b*NN + koff + ik0)*64 + sw0;
    const _Float16*       gk1 = Kf + ((size_t)b*NN + koff + ik1)*64 + sw1;
    const unsigned short* gv0 = Vt + ((size_t)b*64 + ik0)*NN + koff + sw0;
    const unsigned short* gv1 = Vt + ((size_t)b*64 + ik1)*NN + koff + sw1;

#define STAGE(ck, pb) do {                                                          \
    const size_t o64_ = (size_t)(ck)*64;                                            \
    __builtin_amdgcn_global_load_lds(                                               \
        (const __attribute__((address_space(1))) void*)(gk0 + o64_*64),             \
        (__attribute__((address_space(3))) void*)&Kb2[pb][(wv*64)*8], 16, 0, 0);    \
    __builtin_amdgcn_global_load_lds(                                               \
        (const __attribute__((address_space(1))) void*)(gk1 + o64_*64),             \
        (__attribute__((address_space(3))) void*)&Kb2[pb][(256 + wv*64)*8], 16, 0, 0); \
    __builtin_amdgcn_global_load_lds(                                               \
        (const __attribute__((address_space(1))) void*)(gv0 + o64_),                \
        (__attribute__((address_space(3))) void*)&Vb2[pb][(wv*64)*8], 16, 0, 0);    \
    __builtin_amdgcn_global_load_lds(                                               \
        (const __attribute__((address_space(1))) void*)(gv1 + o64_),                \
        (__attribute__((address_space(3))) void*)&Vb2[pb][(256 + wv*64)*8], 16, 0, 0); \
    } while (0)

    STAGE(0, 0);
    __syncthreads();

    for (int ck = 0; ck < NCH; ck++) {
        const int cb = ck & 1;
        if (ck + 1 < NCH) STAGE(ck + 1, cb ^ 1);

        const unsigned short* Kb = Kb2[cb];
        const unsigned short* Vb = Vb2[cb];

        #pragma unroll
        for (int isub = 0; isub < 2; isub++) {
            // ---- S^T tile: A = K[i][c] (i = isub*32 + il), B = Q[c][j] ----
            const int irow = isub*32 + il;
            const unsigned short* kr = Kb + irow*64;
            f32x16 sc;
            #pragma unroll
            for (int r = 0; r < 16; r++) sc[r] = 0.f;
            #pragma unroll
            for (int sl = 0; sl < 4; sl++) {
                half8 kf = *(const half8*)(kr + (((sl*2 + h) ^ (irow & 7)) << 3));
                sc = __builtin_amdgcn_mfma_f32_32x32x16_f16(kf, qfr[sl], sc, 0, 0, 0);
            }

            // ---- softmax numerator, lane-local (j = il); rows i = (r&3)+8*(r>>2)+4h ----
            float pq[16];
            #pragma unroll
            for (int r = 0; r < 16; r++) pq[r] = exp2f(sc[r]);
            #pragma unroll
            for (int r = 0; r < 16; r++) l4[r & 3] += pq[r];

            // ---- P -> bf16 A-fragments in-register (cvt_pk + permlane32_swap) ----
            unsigned wA[8];
            #pragma unroll
            for (int k = 0; k < 8; k++)
                asm("v_cvt_pk_bf16_f32 %0, %1, %2" : "=v"(wA[k]) : "v"(pq[2*k]), "v"(pq[2*k+1]));
            // swap (w0,w2),(w1,w3): after, frag islice0 = [w0,w1,w2,w3]; same for islice1
            asm("v_permlane32_swap_b32 %0, %1" : "+v"(wA[0]), "+v"(wA[2]));
            asm("v_permlane32_swap_b32 %0, %1" : "+v"(wA[1]), "+v"(wA[3]));
            asm("v_permlane32_swap_b32 %0, %1" : "+v"(wA[4]), "+v"(wA[6]));
            asm("v_permlane32_swap_b32 %0, %1" : "+v"(wA[5]), "+v"(wA[7]));

            union { unsigned u[4]; short8 s8; } pa0, pa1;
            pa0.u[0]=wA[0]; pa0.u[1]=wA[1]; pa0.u[2]=wA[2]; pa0.u[3]=wA[3];
            pa1.u[0]=wA[4]; pa1.u[1]=wA[5]; pa1.u[2]=wA[6]; pa1.u[3]=wA[7];

            // ---- PV: A = P^T[j][i], B = V[i][d] ----
            #pragma unroll
            for (int isl = 0; isl < 2; isl++) {
                const short8 paf = isl ? pa1.s8 : pa0.s8;
                const int vc = isub*4 + isl*2 + h;
                #pragma unroll
                for (int dt = 0; dt < 2; dt++) {
                    const int drow = dt*32 + il;
                    short8 vf = *(const short8*)(Vb + drow*64 + ((vc ^ (drow & 7)) << 3));
                    o_acc[dt] = __builtin_amdgcn_mfma_f32_32x32x16_bf16(paf, vf, o_acc[dt], 0, 0, 0);
                }
            }
        }
        __syncthreads();   // drains staged loads (vmcnt) + orders buffer reuse
    }
#undef STAGE

    // ---- epilogue: combine halves, normalize per-split, store ----
    float l_acc  = (l4[0] + l4[1]) + (l4[2] + l4[3]);
    float l_full = l_acc + __shfl_xor(l_acc, 32);
    float inv = 1.0f / l_full;

    const size_t pbase = (size_t)(s*4 + b)*NN + j0w;
    #pragma unroll
    for (int r = 0; r < 16; r++) {
        const int jr = (r & 3) + 8*(r >> 2) + 4*h;
        const float invr = __shfl(inv, jr);
        #pragma unroll
        for (int dt = 0; dt < 2; dt++)
            Po16[(pbase + jr)*64 + dt*32 + il] = (_Float16)(o_acc[dt][r] * invr);
    }
    if (h == 0) Pl[pbase + il] = l_full;
}

// ---------------- Kernel 3: fused combine + output projection + residual ----------------
// grid 512: (b, j-chunk of 32). Inline split-K merge; LDS-transposed epilogue
// so out1/out2 stores and x residual loads are full dwordx4 (128B/8 lanes).
template<int SPLITS>
__global__ __launch_bounds__(256) void outproj_kernel(
    const _Float16* __restrict__ Po16, const float* __restrict__ Pl,
    const _Float16* __restrict__ Wv16,
    const float* __restrict__ x, const float* __restrict__ gamma,
    float* __restrict__ out1, float* __restrict__ out2)
{
    __shared__ float Osh[4][16][36];   // per-wave C-tile staging (36: 2-way banks only)
    const int t    = threadIdx.x;
    const int w    = t >> 6;
    const int lane = t & 63;
    const int lh   = lane & 15;
    const int qd   = lane >> 4;
    const int b    = blockIdx.x >> 7;
    const int j0   = (blockIdx.x & 127) << 5;
    const float g  = gamma[0];

    half8 sb[2][2];
    #pragma unroll
    for (int jt2 = 0; jt2 < 2; jt2++) {
        const int j = j0 + jt2*16 + lh;
        float os[16];
        #pragma unroll
        for (int k = 0; k < 16; k++) os[k] = 0.f;
        float lsum = 0.f;
        #pragma unroll
        for (int s = 0; s < SPLITS; s++) {
            size_t base = ((size_t)(s*4 + b)*NN + j);
            half8 v0 = *(const half8*)(Po16 + base*64 + qd*8);
            half8 v1 = *(const half8*)(Po16 + base*64 + qd*8 + 32);
            float l = Pl[base];
            #pragma unroll
            for (int k = 0; k < 8; k++) {
                os[k]   = fmaf(l, (float)v0[k], os[k]);
                os[8+k] = fmaf(l, (float)v1[k], os[8+k]);
            }
            lsum += l;
        }
        float inv = 1.0f / lsum;
        union { fp16x2 h2[4]; half8 h8; } u0, u1;
        #pragma unroll
        for (int k = 0; k < 4; k++) {
            u0.h2[k] = __builtin_amdgcn_cvt_pkrtz(os[2*k]*inv,   os[2*k+1]*inv);
            u1.h2[k] = __builtin_amdgcn_cvt_pkrtz(os[8+2*k]*inv, os[8+2*k+1]*inv);
        }
        sb[jt2][0] = u0.h8;
        sb[jt2][1] = u1.h8;
    }

    const int o_loc8 = lane >> 3;          // 0..7
    const int j4     = (lane & 7) * 4;     // 0..28

    #pragma unroll 2
    for (int ot8 = 0; ot8 < 8; ot8++) {
        const int ot = w*8 + ot8;
        const size_t wbase = (size_t)(ot*16 + lh)*64 + qd*8;
        half8 a0 = *(const half8*)(Wv16 + wbase);
        half8 a1 = *(const half8*)(Wv16 + wbase + 32);

        f32x4 acc[2];
        #pragma unroll
        for (int jt2 = 0; jt2 < 2; jt2++) {
            acc[jt2][0]=0.f; acc[jt2][1]=0.f; acc[jt2][2]=0.f; acc[jt2][3]=0.f;
            acc[jt2] = __builtin_amdgcn_mfma_f32_16x16x32_f16(a0, sb[jt2][0], acc[jt2], 0, 0, 0);
            acc[jt2] = __builtin_amdgcn_mfma_f32_16x16x32_f16(a1, sb[jt2][1], acc[jt2], 0, 0, 0);
        }

        // stage C tile [o 16][j 32] in per-wave LDS
        #pragma unroll
        for (int jt2 = 0; jt2 < 2; jt2++)
            #pragma unroll
            for (int r = 0; r < 4; r++)
                Osh[w][qd*4 + r][jt2*16 + lh] = acc[jt2][r];
        asm volatile("s_waitcnt lgkmcnt(0)" ::: "memory");

        // read back transposed, vector stores
        #pragma unroll
        for (int rr2 = 0; rr2 < 2; rr2++) {
            const int o_loc = o_loc8 + 8*rr2;
            f32x4 vv = *(const f32x4*)&Osh[w][o_loc][j4];
            const int o  = ot*16 + o_loc;
            const size_t idx = ((size_t)b*CC + o)*NN + j0 + j4;
            f32x4 xv = *(const f32x4*)(x + idx);
            *(f32x4*)(out2 + idx) = vv;
            f32x4 r1;
            r1[0] = fmaf(g, vv[0], xv[0]); r1[1] = fmaf(g, vv[1], xv[1]);
            r1[2] = fmaf(g, vv[2], xv[2]); r1[3] = fmaf(g, vv[3], xv[3]);
            *(f32x4*)(out1 + idx) = r1;
        }
        asm volatile("s_waitcnt lgkmcnt(0)" ::: "memory");
    }
}

extern "C" void kernel_launch(void* const* d_in, const int* in_sizes, int n_in,
                              void* d_out, int out_size, void* d_ws, size_t ws_size,
                              hipStream_t stream) {
    const float* x     = (const float*)d_in[0];
    const float* Wf    = (const float*)d_in[1];
    const float* Wg    = (const float*)d_in[2];
    const float* Wh    = (const float*)d_in[3];
    const float* Wv    = (const float*)d_in[4];
    const float* gamma = (const float*)d_in[5];

    float* out1 = (float*)d_out;
    float* out2 = out1 + (size_t)BB*CC*NN;

    const size_t BND = (size_t)BB*NN*64;   // 1M elements
    const size_t need8 = BND*2*3 + BND*2*8 + (size_t)8*BB*NN*4
                       + (size_t)192*512*2 + (size_t)512*64*2;
    const int SPL = (ws_size >= need8) ? 8 : 4;

    char* wp = (char*)d_ws;
    _Float16*       Kf   = (_Float16*)wp;        wp += BND*2;            // 2 MB
    _Float16*       Qf   = (_Float16*)wp;        wp += BND*2;            // 2 MB
    unsigned short* Vt   = (unsigned short*)wp;  wp += BND*2;            // 2 MB
    _Float16*       Po16 = (_Float16*)wp;        wp += BND*2*SPL;        // 8/16 MB
    float*          Pl   = (float*)wp;           wp += (size_t)SPL*BB*NN*4;
    _Float16*       Wc16 = (_Float16*)wp;        wp += (size_t)192*512*2;
    _Float16*       Wv16 = (_Float16*)wp;

    prep_kernel<<<dim3(64), dim3(256), 0, stream>>>(Wf, Wg, Wh, Wv, Wc16, Wv16);
    proj_kernel<<<dim3(BB*256), dim3(256), 0, stream>>>(x, Wc16, Kf, Qf, Vt);
    if (SPL == 8) {
        attn_kernel<8><<<dim3(128*8), dim3(256), 0, stream>>>(Kf, Qf, Vt, Po16, Pl);
        outproj_kernel<8><<<dim3(512), dim3(256), 0, stream>>>(Po16, Pl, Wv16, x, gamma, out1, out2);
    } else {
        attn_kernel<4><<<dim3(128*4), dim3(256), 0, stream>>>(Kf, Qf, Vt, Po16, Pl);
        outproj_kernel<4><<<dim3(512), dim3(256), 0, stream>>>(Po16, Pl, Wv16, x, gamma, out1, out2);
    }
}

// Round 5
// 162.717 us; speedup vs baseline: 1.0692x; 1.0692x over previous
//
#include <hip/hip_runtime.h>
#include <cstddef>

#define BB 4
#define CC 512
#define NN 4096

using half8  = __attribute__((ext_vector_type(8))) _Float16;
using fp16x2 = __attribute__((ext_vector_type(2))) __fp16;
using short8 = __attribute__((ext_vector_type(8))) short;
using us8    = __attribute__((ext_vector_type(8))) unsigned short;
using f32x4  = __attribute__((ext_vector_type(4))) float;
using f32x16 = __attribute__((ext_vector_type(16))) float;

__device__ __forceinline__ unsigned short f2bf(float x) {
    unsigned int u = __float_as_uint(x);
    u += 0x7fffu + ((u >> 16) & 1u);
    return (unsigned short)(u >> 16);
}

// ---------------- Kernel 0: weight conversion to fp16 ----------------
// Wc16 [192][512] = cat(Wf, Wg*log2e, Wh); Wv16 [512][64]
__global__ __launch_bounds__(256) void prep_kernel(
    const float* __restrict__ Wf, const float* __restrict__ Wg,
    const float* __restrict__ Wh, const float* __restrict__ Wv,
    _Float16* __restrict__ Wc16, _Float16* __restrict__ Wv16)
{
    int idx = blockIdx.x * 256 + threadIdx.x;
    int stride = gridDim.x * 256;
    const int N1 = 192 * 512, N2 = 512 * 64;
    for (int i = idx; i < N1 + N2; i += stride) {
        if (i < N1) {
            int row = i >> 9, c = i & 511;
            const float* src = (row < 64) ? Wf : ((row < 128) ? Wg : Wh);
            float sc = (row >= 64 && row < 128) ? 1.4426950408889634f : 1.0f;
            Wc16[i] = (_Float16)(sc * src[(row & 63) * 512 + c]);
        } else {
            int k = i - N1;
            Wv16[k] = (_Float16)Wv[k];
        }
    }
}

// ---------------- Kernel 1: projections f,g,h — LDS-staged fp16 MFMA ----------------
// grid 512: (b, i-chunk of 32). x tile [64c][32i] fp32 double-buffered in LDS,
// register prefetch of x AND weights one chunk ahead. 2 MFMA per weight load.
// [R1 measured-best version — R4's 16-i variant regressed ~10us: doubled weight
//  re-fetch per block and halved per-wave x-load ILP.]
__global__ __launch_bounds__(256) void proj_kernel(
    const float* __restrict__ x, const _Float16* __restrict__ Wc16,
    _Float16* __restrict__ Kf, _Float16* __restrict__ Qf,
    unsigned short* __restrict__ Vt)
{
    __shared__ float xsT[2][32][68];   // [buf][i][c] (68: 16B-aligned rows, pad)
    const int t    = threadIdx.x;
    const int w    = t >> 6;
    const int lane = t & 63;
    const int lh   = lane & 15;
    const int qd   = lane >> 4;
    const int b    = blockIdx.x >> 7;
    const int i0   = (blockIdx.x & 127) << 5;

    f32x4 acc[3][2];
    #pragma unroll
    for (int ot = 0; ot < 3; ot++)
        #pragma unroll
        for (int it = 0; it < 2; it++) { acc[ot][it][0]=0.f; acc[ot][it][1]=0.f; acc[ot][it][2]=0.f; acc[ot][it][3]=0.f; }

    const int ti8 = t & 7;           // i-group of 4
    const int tc2 = t >> 3;          // c-row 0..31
    const float* xbase = x + (size_t)b*CC*NN + i0 + ti8*4;
    const _Float16* wbase = Wc16 + (size_t)(w*48 + lh)*512 + qd*8;

    float4 st0, st1;
    half8  wcur[2][3], wnxt[2][3];

#define LOADX(ck) do {                                                        \
    st0 = *(const float4*)(xbase + (size_t)((ck)*64 + tc2)*NN);               \
    st1 = *(const float4*)(xbase + (size_t)((ck)*64 + 32 + tc2)*NN);          \
} while (0)
#define STOREX(p_) do {                                                       \
    xsT[p_][ti8*4+0][tc2]    = st0.x; xsT[p_][ti8*4+1][tc2]    = st0.y;       \
    xsT[p_][ti8*4+2][tc2]    = st0.z; xsT[p_][ti8*4+3][tc2]    = st0.w;       \
    xsT[p_][ti8*4+0][32+tc2] = st1.x; xsT[p_][ti8*4+1][32+tc2] = st1.y;       \
    xsT[p_][ti8*4+2][32+tc2] = st1.z; xsT[p_][ti8*4+3][32+tc2] = st1.w;       \
} while (0)
#define LOADW(ck, WD) do {                                                    \
    _Pragma("unroll")                                                         \
    for (int ks_ = 0; ks_ < 2; ks_++)                                         \
        _Pragma("unroll")                                                     \
        for (int ot_ = 0; ot_ < 3; ot_++)                                     \
            WD[ks_][ot_] = *(const half8*)(wbase + (size_t)(ot_*16)*512 + (ck)*64 + ks_*32); \
} while (0)

    LOADX(0); STOREX(0);
    LOADW(0, wcur);
    __syncthreads();

    #pragma unroll
    for (int ck = 0; ck < 8; ck++) {
        const int p = ck & 1;
        if (ck < 7) { LOADX(ck + 1); LOADW(ck + 1, wnxt); }

        #pragma unroll
        for (int ks = 0; ks < 2; ks++) {
            half8 xf[2];
            #pragma unroll
            for (int it = 0; it < 2; it++) {
                const float* xr = &xsT[p][it*16 + lh][ks*32 + qd*8];
                f32x4 xa = *(const f32x4*)xr;
                f32x4 xb = *(const f32x4*)(xr + 4);
                union { fp16x2 h2[4]; half8 h8; } u;
                u.h2[0] = __builtin_amdgcn_cvt_pkrtz(xa[0], xa[1]);
                u.h2[1] = __builtin_amdgcn_cvt_pkrtz(xa[2], xa[3]);
                u.h2[2] = __builtin_amdgcn_cvt_pkrtz(xb[0], xb[1]);
                u.h2[3] = __builtin_amdgcn_cvt_pkrtz(xb[2], xb[3]);
                xf[it] = u.h8;
            }
            #pragma unroll
            for (int ot = 0; ot < 3; ot++)
                #pragma unroll
                for (int it = 0; it < 2; it++)
                    acc[ot][it] = __builtin_amdgcn_mfma_f32_16x16x32_f16(wcur[ks][ot], xf[it], acc[ot][it], 0, 0, 0);
        }

        if (ck < 7) {
            STOREX(p ^ 1);
            #pragma unroll
            for (int ks_ = 0; ks_ < 2; ks_++)
                #pragma unroll
                for (int ot_ = 0; ot_ < 3; ot_++)
                    wcur[ks_][ot_] = wnxt[ks_][ot_];
        }
        __syncthreads();
    }
#undef LOADX
#undef STOREX
#undef LOADW

    #pragma unroll
    for (int ot = 0; ot < 3; ot++) {
        int g16 = w*3 + ot;          // 0..11
        int m   = g16 >> 2;
        int obase = (g16 & 3)*16 + qd*4;
        #pragma unroll
        for (int it = 0; it < 2; it++) {
            int ig = i0 + it*16 + lh;
            #pragma unroll
            for (int r = 0; r < 4; r++) {
                float v = acc[ot][it][r];
                int ol = obase + r;
                if (m == 0)       Kf[((size_t)b*NN + ig)*64 + ol] = (_Float16)v;
                else if (m == 1)  Qf[((size_t)b*NN + ig)*64 + ol] = (_Float16)v;
                else              Vt[((size_t)b*64 + ol)*NN + ig] = f2bf(v);
            }
        }
    }
}

// ---------------- Kernel 2: split-K flash attention, 32x32 swapped-QK^T ----------------
// grid 128*SPLITS: (b, j-tile of 128, split s). 4 waves, wave owns 32 j columns.
// [R1 measured-best version]
template<int SPLITS>
__global__ __launch_bounds__(256, 3) void attn_kernel(
    const _Float16* __restrict__ Kf, const _Float16* __restrict__ Qf,
    const unsigned short* __restrict__ Vt,
    _Float16* __restrict__ Po16, float* __restrict__ Pl)
{
    static_assert(NN % SPLITS == 0, "split");
    constexpr int KS  = NN / SPLITS;   // keys per split
    constexpr int NCH = KS / 64;       // 64-key chunks

    __shared__ __align__(16) unsigned short Kb2[2][64*64];  // [i][c] swizzled 16B blocks
    __shared__ __align__(16) unsigned short Vb2[2][64*64];  // [d][i] swizzled 16B blocks

    const int t    = threadIdx.x;
    const int wv   = t >> 6;
    const int lane = t & 63;
    const int il   = lane & 31;
    const int h    = lane >> 5;

    // bijective XCD swizzle: blocks sharing (b,s) (same K/V) land on one XCD
    const int p  = blockIdx.x;
    const int v  = (p & 7) * (SPLITS * 16) + (p >> 3);
    const int jt = v & 31;
    const int bs = v >> 5;
    const int b  = bs / SPLITS;
    const int s  = bs % SPLITS;
    const int j0w  = jt*128 + wv*32;
    const int koff = s * KS;

    // Q fragments (B-operand), hoisted: lane supplies Q[c = sl*16 + h*8 + e][j = j0w + il]
    half8 qfr[4];
    {
        const _Float16* qp = Qf + ((size_t)b*NN + j0w + il)*64 + h*8;
        #pragma unroll
        for (int sl = 0; sl < 4; sl++) qfr[sl] = *(const half8*)(qp + sl*16);
    }

    f32x16 o_acc[2];
    #pragma unroll
    for (int dt = 0; dt < 2; dt++)
        #pragma unroll
        for (int r = 0; r < 16; r++) o_acc[dt][r] = 0.f;
    float l4[4] = {0.f, 0.f, 0.f, 0.f};

    // Staging bases, hoisted. Two 16B slots per thread per buffer (K and V each):
    // linear LDS dest (wave-uniform base + lane*16), inverse-swizzled global SOURCE
    // (involution: slot c8 holds col block c8^(row&7)).
    const int slot0 = t, slot1 = 256 + t;
    const int ik0 = slot0 >> 3, sw0 = ((slot0 & 7) ^ (ik0 & 7)) << 3;
    const int ik1 = slot1 >> 3, sw1 = ((slot1 & 7) ^ (ik1 & 7)) << 3;
    const _Float16*       gk0 = Kf + ((size_t)b*NN + koff + ik0)*64 + sw0;
    const _Float16*       gk1 = Kf + ((size_t)b*NN + koff + ik1)*64 + sw1;
    const unsigned short* gv0 = Vt + ((size_t)b*64 + ik0)*NN + koff + sw0;
    const unsigned short* gv1 = Vt + ((size_t)b*64 + ik1)*NN + koff + sw1;

#define STAGE(ck, pb) do {                                                          \
    const size_t o64_ = (size_t)(ck)*64;                                            \
    __builtin_amdgcn_global_load_lds(                                               \
        (const __attribute__((address_space(1))) void*)(gk0 + o64_*64),             \
        (__attribute__((address_space(3))) void*)&Kb2[pb][(wv*64)*8], 16, 0, 0);    \
    __builtin_amdgcn_global_load_lds(                                               \
        (const __attribute__((address_space(1))) void*)(gk1 + o64_*64),             \
        (__attribute__((address_space(3))) void*)&Kb2[pb][(256 + wv*64)*8], 16, 0, 0); \
    __builtin_amdgcn_global_load_lds(                                               \
        (const __attribute__((address_space(1))) void*)(gv0 + o64_),                \
        (__attribute__((address_space(3))) void*)&Vb2[pb][(wv*64)*8], 16, 0, 0);    \
    __builtin_amdgcn_global_load_lds(                                               \
        (const __attribute__((address_space(1))) void*)(gv1 + o64_),                \
        (__attribute__((address_space(3))) void*)&Vb2[pb][(256 + wv*64)*8], 16, 0, 0); \
    } while (0)

    STAGE(0, 0);
    __syncthreads();

    for (int ck = 0; ck < NCH; ck++) {
        const int cb = ck & 1;
        if (ck + 1 < NCH) STAGE(ck + 1, cb ^ 1);

        const unsigned short* Kb = Kb2[cb];
        const unsigned short* Vb = Vb2[cb];

        #pragma unroll
        for (int isub = 0; isub < 2; isub++) {
            // ---- S^T tile: A = K[i][c] (i = isub*32 + il), B = Q[c][j] ----
            const int irow = isub*32 + il;
            const unsigned short* kr = Kb + irow*64;
            f32x16 sc;
            #pragma unroll
            for (int r = 0; r < 16; r++) sc[r] = 0.f;
            #pragma unroll
            for (int sl = 0; sl < 4; sl++) {
                half8 kf = *(const half8*)(kr + (((sl*2 + h) ^ (irow & 7)) << 3));
                sc = __builtin_amdgcn_mfma_f32_32x32x16_f16(kf, qfr[sl], sc, 0, 0, 0);
            }

            // ---- softmax numerator, lane-local (j = il); rows i = (r&3)+8*(r>>2)+4h ----
            float pq[16];
            #pragma unroll
            for (int r = 0; r < 16; r++) pq[r] = exp2f(sc[r]);
            #pragma unroll
            for (int r = 0; r < 16; r++) l4[r & 3] += pq[r];

            // ---- P -> bf16 A-fragments in-register (cvt_pk + permlane32_swap) ----
            unsigned wA[8];
            #pragma unroll
            for (int k = 0; k < 8; k++)
                asm("v_cvt_pk_bf16_f32 %0, %1, %2" : "=v"(wA[k]) : "v"(pq[2*k]), "v"(pq[2*k+1]));
            // swap (w0,w2),(w1,w3): after, frag islice0 = [w0,w1,w2,w3]; same for islice1
            asm("v_permlane32_swap_b32 %0, %1" : "+v"(wA[0]), "+v"(wA[2]));
            asm("v_permlane32_swap_b32 %0, %1" : "+v"(wA[1]), "+v"(wA[3]));
            asm("v_permlane32_swap_b32 %0, %1" : "+v"(wA[4]), "+v"(wA[6]));
            asm("v_permlane32_swap_b32 %0, %1" : "+v"(wA[5]), "+v"(wA[7]));

            union { unsigned u[4]; short8 s8; } pa0, pa1;
            pa0.u[0]=wA[0]; pa0.u[1]=wA[1]; pa0.u[2]=wA[2]; pa0.u[3]=wA[3];
            pa1.u[0]=wA[4]; pa1.u[1]=wA[5]; pa1.u[2]=wA[6]; pa1.u[3]=wA[7];

            // ---- PV: A = P^T[j][i], B = V[i][d] ----
            #pragma unroll
            for (int isl = 0; isl < 2; isl++) {
                const short8 paf = isl ? pa1.s8 : pa0.s8;
                const int vc = isub*4 + isl*2 + h;
                #pragma unroll
                for (int dt = 0; dt < 2; dt++) {
                    const int drow = dt*32 + il;
                    short8 vf = *(const short8*)(Vb + drow*64 + ((vc ^ (drow & 7)) << 3));
                    o_acc[dt] = __builtin_amdgcn_mfma_f32_32x32x16_bf16(paf, vf, o_acc[dt], 0, 0, 0);
                }
            }
        }
        __syncthreads();   // drains staged loads (vmcnt) + orders buffer reuse
    }
#undef STAGE

    // ---- epilogue: combine halves, normalize per-split, store ----
    float l_acc  = (l4[0] + l4[1]) + (l4[2] + l4[3]);
    float l_full = l_acc + __shfl_xor(l_acc, 32);
    float inv = 1.0f / l_full;

    const size_t pbase = (size_t)(s*4 + b)*NN + j0w;
    #pragma unroll
    for (int r = 0; r < 16; r++) {
        const int jr = (r & 3) + 8*(r >> 2) + 4*h;
        const float invr = __shfl(inv, jr);
        #pragma unroll
        for (int dt = 0; dt < 2; dt++)
            Po16[(pbase + jr)*64 + dt*32 + il] = (_Float16)(o_acc[dt][r] * invr);
    }
    if (h == 0) Pl[pbase + il] = l_full;
}

// ---------------- Kernel 3: fused combine + output projection + residual ----------------
// grid 512: (b, j-chunk of 32). Inline split-K merge; LDS-transposed epilogue.
// FIX this round: x residual loads (cold HBM, ~800cy) are issued at the TOP of
// each ot8 iteration, before the MFMA + LDS transpose — previously the inline-asm
// lgkmcnt "memory" fence forced them to issue right before use (fully exposed
// latency, 16x per wave).
template<int SPLITS>
__global__ __launch_bounds__(256) void outproj_kernel(
    const _Float16* __restrict__ Po16, const float* __restrict__ Pl,
    const _Float16* __restrict__ Wv16,
    const float* __restrict__ x, const float* __restrict__ gamma,
    float* __restrict__ out1, float* __restrict__ out2)
{
    __shared__ float Osh[4][16][36];   // per-wave C-tile staging (36: 2-way banks only)
    const int t    = threadIdx.x;
    const int w    = t >> 6;
    const int lane = t & 63;
    const int lh   = lane & 15;
    const int qd   = lane >> 4;
    const int b    = blockIdx.x >> 7;
    const int j0   = (blockIdx.x & 127) << 5;
    const float g  = gamma[0];

    half8 sb[2][2];
    #pragma unroll
    for (int jt2 = 0; jt2 < 2; jt2++) {
        const int j = j0 + jt2*16 + lh;
        float os[16];
        #pragma unroll
        for (int k = 0; k < 16; k++) os[k] = 0.f;
        float lsum = 0.f;
        #pragma unroll
        for (int s = 0; s < SPLITS; s++) {
            size_t base = ((size_t)(s*4 + b)*NN + j);
            half8 v0 = *(const half8*)(Po16 + base*64 + qd*8);
            half8 v1 = *(const half8*)(Po16 + base*64 + qd*8 + 32);
            float l = Pl[base];
            #pragma unroll
            for (int k = 0; k < 8; k++) {
                os[k]   = fmaf(l, (float)v0[k], os[k]);
                os[8+k] = fmaf(l, (float)v1[k], os[8+k]);
            }
            lsum += l;
        }
        float inv = 1.0f / lsum;
        union { fp16x2 h2[4]; half8 h8; } u0, u1;
        #pragma unroll
        for (int k = 0; k < 4; k++) {
            u0.h2[k] = __builtin_amdgcn_cvt_pkrtz(os[2*k]*inv,   os[2*k+1]*inv);
            u1.h2[k] = __builtin_amdgcn_cvt_pkrtz(os[8+2*k]*inv, os[8+2*k+1]*inv);
        }
        sb[jt2][0] = u0.h8;
        sb[jt2][1] = u1.h8;
    }

    const int o_loc8 = lane >> 3;          // 0..7
    const int j4     = (lane & 7) * 4;     // 0..28

    #pragma unroll 2
    for (int ot8 = 0; ot8 < 8; ot8++) {
        const int ot = w*8 + ot8;

        // ---- issue x residual loads FIRST: no dependencies, ~800cy HBM latency
        // hides under the MFMA + LDS transpose below ----
        size_t idx[2];
        f32x4  xv[2];
        #pragma unroll
        for (int rr2 = 0; rr2 < 2; rr2++) {
            const int o_loc = o_loc8 + 8*rr2;
            const int o  = ot*16 + o_loc;
            idx[rr2] = ((size_t)b*CC + o)*NN + j0 + j4;
            xv[rr2]  = *(const f32x4*)(x + idx[rr2]);
        }

        const size_t wbase = (size_t)(ot*16 + lh)*64 + qd*8;
        half8 a0 = *(const half8*)(Wv16 + wbase);
        half8 a1 = *(const half8*)(Wv16 + wbase + 32);

        f32x4 acc[2];
        #pragma unroll
        for (int jt2 = 0; jt2 < 2; jt2++) {
            acc[jt2][0]=0.f; acc[jt2][1]=0.f; acc[jt2][2]=0.f; acc[jt2][3]=0.f;
            acc[jt2] = __builtin_amdgcn_mfma_f32_16x16x32_f16(a0, sb[jt2][0], acc[jt2], 0, 0, 0);
            acc[jt2] = __builtin_amdgcn_mfma_f32_16x16x32_f16(a1, sb[jt2][1], acc[jt2], 0, 0, 0);
        }

        // stage C tile [o 16][j 32] in per-wave LDS
        #pragma unroll
        for (int jt2 = 0; jt2 < 2; jt2++)
            #pragma unroll
            for (int r = 0; r < 4; r++)
                Osh[w][qd*4 + r][jt2*16 + lh] = acc[jt2][r];
        asm volatile("s_waitcnt lgkmcnt(0)" ::: "memory");

        // read back transposed, vector stores (x already in registers)
        #pragma unroll
        for (int rr2 = 0; rr2 < 2; rr2++) {
            const int o_loc = o_loc8 + 8*rr2;
            f32x4 v = *(const f32x4*)&Osh[w][o_loc][j4];
            *(f32x4*)(out2 + idx[rr2]) = v;
            f32x4 r1;
            r1[0] = fmaf(g, v[0], xv[rr2][0]); r1[1] = fmaf(g, v[1], xv[rr2][1]);
            r1[2] = fmaf(g, v[2], xv[rr2][2]); r1[3] = fmaf(g, v[3], xv[rr2][3]);
            *(f32x4*)(out1 + idx[rr2]) = r1;
        }
        asm volatile("s_waitcnt lgkmcnt(0)" ::: "memory");  // WAR guard before next Osh write
    }
}

extern "C" void kernel_launch(void* const* d_in, const int* in_sizes, int n_in,
                              void* d_out, int out_size, void* d_ws, size_t ws_size,
                              hipStream_t stream) {
    const float* x     = (const float*)d_in[0];
    const float* Wf    = (const float*)d_in[1];
    const float* Wg    = (const float*)d_in[2];
    const float* Wh    = (const float*)d_in[3];
    const float* Wv    = (const float*)d_in[4];
    const float* gamma = (const float*)d_in[5];

    float* out1 = (float*)d_out;
    float* out2 = out1 + (size_t)BB*CC*NN;

    const size_t BND = (size_t)BB*NN*64;   // 1M elements
    const size_t need8 = BND*2*3 + BND*2*8 + (size_t)8*BB*NN*4
                       + (size_t)192*512*2 + (size_t)512*64*2;
    const int SPL = (ws_size >= need8) ? 8 : 4;

    char* wp = (char*)d_ws;
    _Float16*       Kf   = (_Float16*)wp;        wp += BND*2;            // 2 MB
    _Float16*       Qf   = (_Float16*)wp;        wp += BND*2;            // 2 MB
    unsigned short* Vt   = (unsigned short*)wp;  wp += BND*2;            // 2 MB
    _Float16*       Po16 = (_Float16*)wp;        wp += BND*2*SPL;        // 8/16 MB
    float*          Pl   = (float*)wp;           wp += (size_t)SPL*BB*NN*4;
    _Float16*       Wc16 = (_Float16*)wp;        wp += (size_t)192*512*2;
    _Float16*       Wv16 = (_Float16*)wp;

    prep_kernel<<<dim3(64), dim3(256), 0, stream>>>(Wf, Wg, Wh, Wv, Wc16, Wv16);
    proj_kernel<<<dim3(BB*128), dim3(256), 0, stream>>>(x, Wc16, Kf, Qf, Vt);
    if (SPL == 8) {
        attn_kernel<8><<<dim3(128*8), dim3(256), 0, stream>>>(Kf, Qf, Vt, Po16, Pl);
        outproj_kernel<8><<<dim3(512), dim3(256), 0, stream>>>(Po16, Pl, Wv16, x, gamma, out1, out2);
    } else {
        attn_kernel<4><<<dim3(128*4), dim3(256), 0, stream>>>(Kf, Qf, Vt, Po16, Pl);
        outproj_kernel<4><<<dim3(512), dim3(256), 0, stream>>>(Po16, Pl, Wv16, x, gamma, out1, out2);
    }
}